// Round 15
// baseline (132.275 us; speedup 1.0000x reference)
//
#include <hip/hip_runtime.h>
#include <stdint.h>

#define Bn 2048
#define Dn 1024
#define Hn 2048
#define On 512
#define En 8

typedef __bf16 bf16x8 __attribute__((ext_vector_type(8)));
typedef float f32x4 __attribute__((ext_vector_type(4)));
typedef unsigned short ushort_t;
typedef ushort_t ushort8v __attribute__((ext_vector_type(8)));

__device__ __forceinline__ ushort_t f2bf(float v) {
  union { float f; uint32_t u; } a; a.f = v;
  uint32_t u = a.u;
  return (ushort_t)((u + 0x7fffu + ((u >> 16) & 1u)) >> 16);  // RNE, finite inputs
}

__device__ __forceinline__ void gload16(const void* g, void* l) {
  __builtin_amdgcn_global_load_lds((const uint32_t*)g, (uint32_t*)l, 16, 0, 0);
}

// ---------------- init: zero counts/cursors every launch (determinism) ----------------
__global__ void init_kernel(int* counts, int* cursors) {
  int t = threadIdx.x;
  if (t < En) { counts[t] = 0; cursors[t] = 0; }
}

// ================= fused prep: gating+x-cast | tcast fc1_w | tcast fc2_w =================
// tcast blocks now process a 64x256 strip (4 sequential 64x64 sub-tiles, LDS reused).
#define NB_G (Bn / 8)
#define NB_T1 ((Dn / 64) * (Hn / 256) * En)
#define NB_T2 ((Hn / 64) * (On / 256) * En)

// 64x64 transpose+cast sub-tile; writes vectorized to 16B/lane (2x ushort8 per thread).
__device__ __forceinline__ void tcast64(const float* __restrict__ inp, ushort_t* __restrict__ outp,
                                        int R, int C, int r0, int c0, float* tile /*64x65*/) {
  int t = threadIdx.x;
  int rr = t >> 4;          // 0..15
  int cc4 = (t & 15) * 4;   // 0..60
#pragma unroll
  for (int j = 0; j < 4; j++) {
    float4 v = *(const float4*)&inp[(size_t)(r0 + j * 16 + rr) * C + c0 + cc4];
    float* tp = &tile[(j * 16 + rr) * 65 + cc4];
    tp[0] = v.x; tp[1] = v.y; tp[2] = v.z; tp[3] = v.w;
  }
  __syncthreads();
  int orow = t >> 2, g = t & 3;
  ushort8v o0, o1;
#pragma unroll
  for (int i = 0; i < 8; i++) o0[i] = f2bf(tile[(g * 16 + i) * 65 + orow]);
#pragma unroll
  for (int i = 0; i < 8; i++) o1[i] = f2bf(tile[(g * 16 + 8 + i) * 65 + orow]);
  ushort_t* op = &outp[(size_t)(c0 + orow) * R + r0 + g * 16];
  *(ushort8v*)op = o0;
  *(ushort8v*)(op + 8) = o1;
}

__device__ __forceinline__ void tcast_strip(const float* __restrict__ inp,
                                            ushort_t* __restrict__ outp, int R, int C,
                                            int r0, int c0, float* tile) {
#pragma unroll
  for (int s = 0; s < 4; s++) {
    if (s) __syncthreads();  // protect LDS reuse
    tcast64(inp, outp, R, C, r0, c0 + s * 64, tile);
  }
}

__global__ __launch_bounds__(256) void prep_kernel(
    const float* __restrict__ x, const float* __restrict__ wg,
    const float* __restrict__ fc1w, const float* __restrict__ fc2w,
    ushort_t* __restrict__ x_bf, ushort_t* __restrict__ w1t, ushort_t* __restrict__ w2t,
    int* __restrict__ top_idx, float* __restrict__ gates, int* __restrict__ counts) {
  __shared__ float smem[En * Dn];  // 32 KB
  __shared__ int lcnt[En];
  int bid = blockIdx.x;
  int t = threadIdx.x;

  if (bid < NB_G) {
    float* wgs = smem;
    for (int i = t; i < Dn * En; i += 256) {
      int d = i >> 3, e = i & 7;
      wgs[e * Dn + d] = wg[i];  // wg is [d][e]
    }
    if (t < En) lcnt[t] = 0;
    __syncthreads();
    int w = t >> 6, lane = t & 63;
#pragma unroll
    for (int r = 0; r < 2; r++) {
      int b = bid * 8 + w * 2 + r;
      const float* xr = x + (size_t)b * Dn;
      ushort_t* xo = x_bf + (size_t)b * Dn;
      float xv[16];
#pragma unroll
      for (int j = 0; j < 16; j++) xv[j] = xr[lane + j * 64];
      float acc[En];
#pragma unroll
      for (int e = 0; e < En; e++) acc[e] = 0.f;
#pragma unroll
      for (int j = 0; j < 16; j++) {
        int d = lane + j * 64;
        xo[d] = f2bf(xv[j]);
#pragma unroll
        for (int e = 0; e < En; e++) acc[e] += xv[j] * wgs[e * Dn + d];
      }
#pragma unroll
      for (int off = 32; off; off >>= 1) {
#pragma unroll
        for (int e = 0; e < En; e++) acc[e] += __shfl_down(acc[e], off);
      }
      if (lane == 0) {
        float best = -1e30f, second = -1e30f; int bi = 0, si = 0;
#pragma unroll
        for (int e = 0; e < En; e++) {
          float l = acc[e];
          if (l > best) { second = best; si = bi; best = l; bi = e; }
          else if (l > second) { second = l; si = e; }
        }
        float e1 = expf(second - best);
        float inv = 1.f / (1.f + e1);
        top_idx[2 * b] = bi; top_idx[2 * b + 1] = si;
        gates[2 * b] = inv;  gates[2 * b + 1] = e1 * inv;
        atomicAdd(&lcnt[bi], 1);
        atomicAdd(&lcnt[si], 1);
      }
    }
    __syncthreads();
    if (t < En) {
      int c = lcnt[t];
      if (c) atomicAdd(&counts[t], c);
    }
  } else if (bid < NB_G + NB_T1) {
    int idx = bid - NB_G;
    constexpr int TPE = (Dn / 64) * (Hn / 256);
    int z = idx / TPE, rem = idx % TPE;
    int r0 = (rem / (Hn / 256)) * 64, c0 = (rem % (Hn / 256)) * 256;
    tcast_strip(fc1w + (size_t)z * Dn * Hn, w1t + (size_t)z * Dn * Hn, Dn, Hn, r0, c0, smem);
  } else {
    int idx = bid - NB_G - NB_T1;
    constexpr int TPE = (Hn / 64) * (On / 256);
    int z = idx / TPE, rem = idx % TPE;
    int r0 = (rem / (On / 256)) * 64, c0 = (rem % (On / 256)) * 256;
    tcast_strip(fc2w + (size_t)z * Hn * On, w2t + (size_t)z * Hn * On, Hn, On, r0, c0, smem);
  }
}

// ---------------- offsets (exclusive prefix over 8 counts) ----------------
__global__ void offsets_kernel(const int* counts, int* offsets, int* cursors) {
  if (threadIdx.x == 0) {
    int s = 0;
    for (int e = 0; e < En; e++) { offsets[e] = s; s += counts[e]; }
  }
  if (threadIdx.x < En) cursors[threadIdx.x] = 0;
}

// ---------------- assign rows to compact slots ----------------
__global__ void assign_kernel(const int* __restrict__ top_idx, const int* __restrict__ offsets,
                              int* cursors, int* __restrict__ s2r, int* __restrict__ r2s) {
  int b = blockIdx.x * 256 + threadIdx.x;
  if (b >= Bn) return;
#pragma unroll
  for (int k = 0; k < 2; k++) {
    int e = top_idx[2 * b + k];
    int pos = atomicAdd(&cursors[e], 1);
    int slot = offsets[e] + pos;
    s2r[slot] = b;
    r2s[2 * b + k] = slot;
  }
}

// ---- grouped GEMM: 64x64 x BK=128 tile, 4 waves (2Mx2N), mfma 16x16x32 bf16 ----
// BK=128: 8 K-steps (vs 16) with staged bytes unchanged -> per-step latency component
// amortized 2x. 32 KB LDS single-buffer, launch_bounds(256,4) keeps >=4 blocks/CU.
// Swizzle: 16 slots/row; slot s of row r holds global 16B-group (s ^ (r&15));
// staged via linear-dest gload_lds + pre-swizzled source (rule #21).
template <bool GATHER, bool FC1, int N, int K, int SPLITK>
__global__ __launch_bounds__(256, 4) void moe_gemm_kernel(
    const ushort_t* __restrict__ A, const ushort_t* __restrict__ WT,
    const float* __restrict__ bias, const int* __restrict__ offsets,
    const int* __restrict__ counts, const int* __restrict__ s2r,
    ushort_t* __restrict__ outH, float* __restrict__ outL, float* __restrict__ outL2) {
  constexpr int NBL = N / 64;
  constexpr int KS = K / SPLITK;
  constexpr int NT = KS / 128;
  int e = blockIdx.z;
  int cnt = counts[e];
  int rb = blockIdx.y;
  if (rb * 64 >= cnt) return;
  int base = offsets[e];
  int ks = blockIdx.x / NBL;
  int nb = (blockIdx.x % NBL) * 64;
  int k0 = ks * KS;
  __shared__ __align__(16) ushort_t As[64 * 128];  // 16 KB
  __shared__ __align__(16) ushort_t Bs[64 * 128];  // 16 KB
  int t = threadIdx.x;
  int lane = t & 63, w = t >> 6;
  int wr = w >> 1, wc = w & 1;

  // staging: pass i covers rows i*16 + (t>>4); slot t&15 holds swizzled 16B group
  int srow = t >> 4;                         // 0..15
  int scol = ((t & 15) ^ srow) * 8;          // pre-swizzled global column (elements)

  const ushort_t* aptr[4];
#pragma unroll
  for (int i = 0; i < 4; i++) {
    int lr = rb * 64 + i * 16 + srow;
    int lrc = lr < cnt ? lr : cnt - 1;
    int slot = base + lrc;
    int row = GATHER ? s2r[slot] : slot;
    aptr[i] = A + (size_t)row * K + k0 + scol;
  }
  const ushort_t* bptr = WT + ((size_t)e * N + nb + srow) * K + k0 + scol;

  f32x4 zero = {0.f, 0.f, 0.f, 0.f};
  f32x4 acc[2][2];
#pragma unroll
  for (int m = 0; m < 2; m++)
#pragma unroll
    for (int n = 0; n < 2; n++) acc[m][n] = zero;

  int a_r = wr * 32 + (lane & 15);   // A fragment row base (wave rows: wr*32..+31)
  int b_r = wc * 32 + (lane & 15);   // B fragment row base (wave cols: wc*32..+31)
  int axor = lane & 15;              // row&15 (row bases mult of 16 -> invariant)
  int c16 = lane >> 4;               // 16B-slot sub-index within row (0..3)

  for (int kt = 0; kt < NT; kt++) {
#pragma unroll
    for (int i = 0; i < 4; i++) gload16(aptr[i] + kt * 128, &As[i * 2048 + t * 8]);
#pragma unroll
    for (int i = 0; i < 4; i++)
      gload16(bptr + (size_t)i * 16 * K + kt * 128, &Bs[i * 2048 + t * 8]);
    __syncthreads();  // drains vmcnt before LDS reads
#pragma unroll
    for (int kk = 0; kk < 4; kk++) {
      bf16x8 af[2], bfr[2];
#pragma unroll
      for (int m = 0; m < 2; m++)
        af[m] = *(const bf16x8*)((const char*)As + (a_r + m * 16) * 256 +
                                 (((kk * 4 + c16) ^ axor) << 4));
#pragma unroll
      for (int n = 0; n < 2; n++)
        bfr[n] = *(const bf16x8*)((const char*)Bs + (b_r + n * 16) * 256 +
                                  (((kk * 4 + c16) ^ axor) << 4));
#pragma unroll
      for (int m = 0; m < 2; m++)
#pragma unroll
        for (int n = 0; n < 2; n++)
          acc[m][n] = __builtin_amdgcn_mfma_f32_16x16x32_bf16(af[m], bfr[n], acc[m][n], 0, 0, 0);
    }
    __syncthreads();  // protect LDS before next stage
  }

  // epilogue: D layout col=lane&15, row=(lane>>4)*4+i
  float* dst = (SPLITK > 1 && ks > 0) ? (outL2 + (size_t)(ks - 1) * (2 * Bn * On)) : outL;
  int lr0 = rb * 64 + wr * 32;
#pragma unroll
  for (int m = 0; m < 2; m++) {
#pragma unroll
    for (int i = 0; i < 4; i++) {
      int lr = lr0 + m * 16 + (lane >> 4) * 4 + i;
      if (lr < cnt) {
        int slot = base + lr;
#pragma unroll
        for (int n = 0; n < 2; n++) {
          int col = nb + wc * 32 + n * 16 + (lane & 15);
          float v = acc[m][n][i] + (ks == 0 ? bias[e * N + col] : 0.f);
          if (FC1) {
            float g = 0.5f * v * (1.0f + erff(v * 0.70710678118654752f));
            outH[(size_t)slot * N + col] = f2bf(g);
          } else {
            dst[(size_t)slot * N + col] = v;
          }
        }
      }
    }
  }
}

// ---------------- combine: sum 2 split-K partials, logsoftmax over O=512, weighted sum ----------------
__device__ __forceinline__ float blk_reduce(float v, bool ismax) {
  __shared__ float sbuf[4];
  int lane = threadIdx.x & 63, w = threadIdx.x >> 6;
#pragma unroll
  for (int off = 32; off; off >>= 1) {
    float o = __shfl_down(v, off);
    v = ismax ? fmaxf(v, o) : (v + o);
  }
  __syncthreads();
  if (lane == 0) sbuf[w] = v;
  __syncthreads();
  float r = sbuf[0];
#pragma unroll
  for (int i = 1; i < 4; i++) r = ismax ? fmaxf(r, sbuf[i]) : (r + sbuf[i]);
  return r;
}

__global__ void combine_kernel(const float* __restrict__ l2a, const float* __restrict__ l2b,
                               const int* __restrict__ r2s, const float* __restrict__ gates,
                               float* __restrict__ out) {
  int b = blockIdx.x, t = threadIdx.x;
  float c0 = 0.f, c1 = 0.f;
#pragma unroll
  for (int k = 0; k < 2; k++) {
    int slot = r2s[2 * b + k];
    float g = gates[2 * b + k];
    const float* lp0 = l2a + (size_t)slot * On;
    const float* lp1 = l2b + (size_t)slot * On;
    float v0 = lp0[t] + lp1[t];
    float v1 = lp0[t + 256] + lp1[t + 256];
    float m = blk_reduce(fmaxf(v0, v1), true);
    float s = blk_reduce(expf(v0 - m) + expf(v1 - m), false);
    float lse = m + logf(s);
    c0 += g * expf(v0 - lse);
    c1 += g * expf(v1 - lse);
  }
  const float EPSv = 2.220446049250313e-16f;
  out[(size_t)b * On + t] = logf(fmaxf(c0, EPSv));
  out[(size_t)b * On + t + 256] = logf(fmaxf(c1, EPSv));
}

extern "C" void kernel_launch(void* const* d_in, const int* in_sizes, int n_in,
                              void* d_out, int out_size, void* d_ws, size_t ws_size,
                              hipStream_t stream) {
  const float* x = (const float*)d_in[0];
  const float* wgate = (const float*)d_in[1];
  const float* fc1w = (const float*)d_in[2];
  const float* fc1b = (const float*)d_in[3];
  const float* fc2w = (const float*)d_in[4];
  const float* fc2b = (const float*)d_in[5];
  float* out = (float*)d_out;

  char* ws = (char*)d_ws;
  size_t o = 0;
  ushort_t* x_bf = (ushort_t*)(ws + o); o += (size_t)Bn * Dn * 2;        // 4 MB
  ushort_t* w1t  = (ushort_t*)(ws + o); o += (size_t)En * Hn * Dn * 2;   // 32 MB [E][H][D]
  ushort_t* w2t  = (ushort_t*)(ws + o); o += (size_t)En * On * Hn * 2;   // 16 MB [E][O][H]
  ushort_t* hbuf = (ushort_t*)(ws + o); o += (size_t)2 * Bn * Hn * 2;    // 16 MB [slot][H]
  float* l2buf   = (float*)(ws + o);    o += (size_t)2 * Bn * On * 4;    // 8 MB (split-K partial 0)
  int* top_idx   = (int*)(ws + o);      o += (size_t)Bn * 2 * 4;
  float* gates   = (float*)(ws + o);    o += (size_t)Bn * 2 * 4;
  int* r2s       = (int*)(ws + o);      o += (size_t)Bn * 2 * 4;
  int* s2r       = (int*)(ws + o);      o += (size_t)2 * Bn * 4;
  int* counts    = (int*)(ws + o);      o += 64;
  int* offsets   = (int*)(ws + o);      o += 64;
  int* cursors   = (int*)(ws + o);      o += 64;
  // split-K partial 1 (8 MB) aliases w1t (32 MB): w1t is fully consumed by fc1
  // (completes before fc2 starts, same stream) and rewritten by prep each launch.
  float* l2buf1  = (float*)w1t;

  hipLaunchKernelGGL(init_kernel, dim3(1), dim3(64), 0, stream, counts, cursors);
  hipLaunchKernelGGL(prep_kernel, dim3(NB_G + NB_T1 + NB_T2), dim3(256), 0, stream,
                     x, wgate, fc1w, fc2w, x_bf, w1t, w2t, top_idx, gates, counts);
  hipLaunchKernelGGL(offsets_kernel, dim3(1), dim3(64), 0, stream, counts, offsets, cursors);
  hipLaunchKernelGGL(assign_kernel, dim3(Bn / 256), dim3(256), 0, stream,
                     top_idx, offsets, cursors, s2r, r2s);
  hipLaunchKernelGGL((moe_gemm_kernel<true, true, Hn, Dn, 1>), dim3(Hn / 64, 32, En), dim3(256),
                     0, stream, x_bf, w1t, fc1b, offsets, counts, s2r, hbuf, (float*)nullptr,
                     (float*)nullptr);
  hipLaunchKernelGGL((moe_gemm_kernel<false, false, On, Hn, 2>), dim3((On / 64) * 2, 32, En),
                     dim3(256), 0, stream, hbuf, w2t, fc2b, offsets, counts, s2r,
                     (ushort_t*)nullptr, l2buf, l2buf1);
  hipLaunchKernelGGL(combine_kernel, dim3(Bn), dim3(256), 0, stream, l2buf, l2buf1, r2s, gates, out);
}

// Round 16
// 124.886 us; speedup vs baseline: 1.0592x; 1.0592x over previous
//
#include <hip/hip_runtime.h>
#include <stdint.h>

#define Bn 2048
#define Dn 1024
#define Hn 2048
#define On 512
#define En 8

typedef __bf16 bf16x8 __attribute__((ext_vector_type(8)));
typedef float f32x4 __attribute__((ext_vector_type(4)));
typedef unsigned short ushort_t;
typedef ushort_t ushort8v __attribute__((ext_vector_type(8)));
typedef unsigned char u8;

__device__ __forceinline__ ushort_t f2bf(float v) {
  union { float f; uint32_t u; } a; a.f = v;
  uint32_t u = a.u;
  return (ushort_t)((u + 0x7fffu + ((u >> 16) & 1u)) >> 16);  // RNE, finite inputs
}

__device__ __forceinline__ void gload16(const void* g, void* l) {
  __builtin_amdgcn_global_load_lds((const uint32_t*)g, (uint32_t*)l, 16, 0, 0);
}

// pack 4 floats -> 4 fp8 e4m3 in one dword
__device__ __forceinline__ int pk4_fp8(float a, float b, float c, float d) {
  int w = __builtin_amdgcn_cvt_pk_fp8_f32(a, b, 0, false);
  w = __builtin_amdgcn_cvt_pk_fp8_f32(c, d, w, true);
  return w;
}

// ---------------- init: zero counts/cursors every launch (determinism) ----------------
__global__ void init_kernel(int* counts, int* cursors) {
  int t = threadIdx.x;
  if (t < En) { counts[t] = 0; cursors[t] = 0; }
}

// ---------------- cast x f32 -> fp8 (16 contiguous elems per thread) ----------------
__global__ __launch_bounds__(256) void cast_x8_kernel(const float* __restrict__ in,
                                                      u8* __restrict__ out) {
  int i = blockIdx.x * 256 + threadIdx.x;
  const float4* p = (const float4*)in + (size_t)i * 4;
  float4 a = p[0], b = p[1], c = p[2], d = p[3];
  int4 o;
  o.x = pk4_fp8(a.x, a.y, a.z, a.w);
  o.y = pk4_fp8(b.x, b.y, b.z, b.w);
  o.z = pk4_fp8(c.x, c.y, c.z, c.w);
  o.w = pk4_fp8(d.x, d.y, d.z, d.w);
  *(int4*)(out + (size_t)i * 16) = o;
}

// ================= fused prep: gating | tcast fc1_w (fp8, x64) | tcast fc2_w (bf16) =======
#define NB_G (Bn / 8)
#define NB_T1 ((Dn / 64) * (Hn / 64) * En)
#define NB_T2 ((Hn / 64) * (On / 64) * En)
#define W1SCALE 64.0f

// 64x64 transpose tile -> bf16 out, writes 2x16B per thread
__device__ __forceinline__ void tcast64_bf(const float* __restrict__ inp,
                                           ushort_t* __restrict__ outp,
                                           int R, int C, int r0, int c0, float* tile) {
  int t = threadIdx.x;
  int rr = t >> 4, cc4 = (t & 15) * 4;
#pragma unroll
  for (int j = 0; j < 4; j++) {
    float4 v = *(const float4*)&inp[(size_t)(r0 + j * 16 + rr) * C + c0 + cc4];
    float* tp = &tile[(j * 16 + rr) * 65 + cc4];
    tp[0] = v.x; tp[1] = v.y; tp[2] = v.z; tp[3] = v.w;
  }
  __syncthreads();
  int orow = t >> 2, g = t & 3;
  ushort8v o0, o1;
#pragma unroll
  for (int i = 0; i < 8; i++) o0[i] = f2bf(tile[(g * 16 + i) * 65 + orow]);
#pragma unroll
  for (int i = 0; i < 8; i++) o1[i] = f2bf(tile[(g * 16 + 8 + i) * 65 + orow]);
  ushort_t* op = &outp[(size_t)(c0 + orow) * R + r0 + g * 16];
  *(ushort8v*)op = o0;
  *(ushort8v*)(op + 8) = o1;
}

// 64x64 transpose tile -> fp8 out (scaled by W1SCALE), writes 16B per thread
__device__ __forceinline__ void tcast64_f8(const float* __restrict__ inp,
                                           u8* __restrict__ outp,
                                           int R, int C, int r0, int c0, float* tile) {
  int t = threadIdx.x;
  int rr = t >> 4, cc4 = (t & 15) * 4;
#pragma unroll
  for (int j = 0; j < 4; j++) {
    float4 v = *(const float4*)&inp[(size_t)(r0 + j * 16 + rr) * C + c0 + cc4];
    float* tp = &tile[(j * 16 + rr) * 65 + cc4];
    tp[0] = v.x; tp[1] = v.y; tp[2] = v.z; tp[3] = v.w;
  }
  __syncthreads();
  int orow = t >> 2, g = t & 3;
  int4 o;
#pragma unroll
  for (int q = 0; q < 4; q++) {
    float v0 = tile[(g * 16 + q * 4 + 0) * 65 + orow] * W1SCALE;
    float v1 = tile[(g * 16 + q * 4 + 1) * 65 + orow] * W1SCALE;
    float v2 = tile[(g * 16 + q * 4 + 2) * 65 + orow] * W1SCALE;
    float v3 = tile[(g * 16 + q * 4 + 3) * 65 + orow] * W1SCALE;
    ((int*)&o)[q] = pk4_fp8(v0, v1, v2, v3);
  }
  *(int4*)&outp[(size_t)(c0 + orow) * R + r0 + g * 16] = o;
}

__global__ __launch_bounds__(256) void prep_kernel(
    const float* __restrict__ x, const float* __restrict__ wg,
    const float* __restrict__ fc1w, const float* __restrict__ fc2w,
    u8* __restrict__ w1t8, ushort_t* __restrict__ w2t,
    int* __restrict__ top_idx, float* __restrict__ gates, int* __restrict__ counts) {
  __shared__ float smem[En * Dn];  // 32 KB
  __shared__ int lcnt[En];
  int bid = blockIdx.x;
  int t = threadIdx.x;

  if (bid < NB_G) {
    float* wgs = smem;
    for (int i = t; i < Dn * En; i += 256) {
      int d = i >> 3, e = i & 7;
      wgs[e * Dn + d] = wg[i];  // wg is [d][e]
    }
    if (t < En) lcnt[t] = 0;
    __syncthreads();
    int w = t >> 6, lane = t & 63;
#pragma unroll
    for (int r = 0; r < 2; r++) {
      int b = bid * 8 + w * 2 + r;
      const float* xr = x + (size_t)b * Dn;
      float xv[16];
#pragma unroll
      for (int j = 0; j < 16; j++) xv[j] = xr[lane + j * 64];
      float acc[En];
#pragma unroll
      for (int e = 0; e < En; e++) acc[e] = 0.f;
#pragma unroll
      for (int j = 0; j < 16; j++) {
        int d = lane + j * 64;
#pragma unroll
        for (int e = 0; e < En; e++) acc[e] += xv[j] * wgs[e * Dn + d];
      }
#pragma unroll
      for (int off = 32; off; off >>= 1) {
#pragma unroll
        for (int e = 0; e < En; e++) acc[e] += __shfl_down(acc[e], off);
      }
      if (lane == 0) {
        float best = -1e30f, second = -1e30f; int bi = 0, si = 0;
#pragma unroll
        for (int e = 0; e < En; e++) {
          float l = acc[e];
          if (l > best) { second = best; si = bi; best = l; bi = e; }
          else if (l > second) { second = l; si = e; }
        }
        float e1 = expf(second - best);
        float inv = 1.f / (1.f + e1);
        top_idx[2 * b] = bi; top_idx[2 * b + 1] = si;
        gates[2 * b] = inv;  gates[2 * b + 1] = e1 * inv;
        atomicAdd(&lcnt[bi], 1);
        atomicAdd(&lcnt[si], 1);
      }
    }
    __syncthreads();
    if (t < En) {
      int c = lcnt[t];
      if (c) atomicAdd(&counts[t], c);
    }
  } else if (bid < NB_G + NB_T1) {
    int idx = bid - NB_G;
    constexpr int TPE = (Dn / 64) * (Hn / 64);
    int z = idx / TPE, rem = idx % TPE;
    int r0 = (rem / (Hn / 64)) * 64, c0 = (rem % (Hn / 64)) * 64;
    tcast64_f8(fc1w + (size_t)z * Dn * Hn, w1t8 + (size_t)z * Dn * Hn, Dn, Hn, r0, c0, smem);
  } else {
    int idx = bid - NB_G - NB_T1;
    constexpr int TPE = (Hn / 64) * (On / 64);
    int z = idx / TPE, rem = idx % TPE;
    int r0 = (rem / (On / 64)) * 64, c0 = (rem % (On / 64)) * 64;
    tcast64_bf(fc2w + (size_t)z * Hn * On, w2t + (size_t)z * Hn * On, Hn, On, r0, c0, smem);
  }
}

// ---------------- offsets (exclusive prefix over 8 counts) ----------------
__global__ void offsets_kernel(const int* counts, int* offsets, int* cursors) {
  if (threadIdx.x == 0) {
    int s = 0;
    for (int e = 0; e < En; e++) { offsets[e] = s; s += counts[e]; }
  }
  if (threadIdx.x < En) cursors[threadIdx.x] = 0;
}

// ---------------- assign rows to compact slots ----------------
__global__ void assign_kernel(const int* __restrict__ top_idx, const int* __restrict__ offsets,
                              int* cursors, int* __restrict__ s2r, int* __restrict__ r2s) {
  int b = blockIdx.x * 256 + threadIdx.x;
  if (b >= Bn) return;
#pragma unroll
  for (int k = 0; k < 2; k++) {
    int e = top_idx[2 * b + k];
    int pos = atomicAdd(&cursors[e], 1);
    int slot = offsets[e] + pos;
    s2r[slot] = b;
    r2s[2 * b + k] = slot;
  }
}

// ---- fc1 fp8 GEMM: 64x64xBK64 tile, 4 waves (2Mx2N), mfma_f32_16x16x32_fp8_fp8 ----
// Staged bytes HALVE vs bf16 (8 KB LDS, 1 gload/operand/step). W1 pre-scaled x64 ->
// epilogue multiplies acc by 1/64 before bias+GELU. Swizzle for 64-B fp8 rows:
// 16B slot s of row r holds global slot (s ^ ((r>>1)&3)); spread over (r&1)-alternating
// bank base -> rows 0..7 distinct, uniform 2-way on reads (free, m136).
__global__ __launch_bounds__(256, 8) void fc1_fp8_kernel(
    const u8* __restrict__ A, const u8* __restrict__ WT,
    const float* __restrict__ bias, const int* __restrict__ offsets,
    const int* __restrict__ counts, const int* __restrict__ s2r,
    ushort_t* __restrict__ outH) {
  constexpr int K = Dn;        // 1024 fp8 bytes per row
  constexpr int NT = K / 64;   // 16 steps
  int e = blockIdx.z;
  int cnt = counts[e];
  int rb = blockIdx.y;
  if (rb * 64 >= cnt) return;
  int base = offsets[e];
  int nb = blockIdx.x * 64;
  __shared__ __align__(16) u8 As[64 * 64];  // 4 KB
  __shared__ __align__(16) u8 Bs[64 * 64];  // 4 KB
  int t = threadIdx.x;
  int lane = t & 63, w = t >> 6;
  int wr = w >> 1, wc = w & 1;

  int srow = t >> 2;                           // 0..63 staging row
  int sslot = (t & 3) ^ ((srow >> 1) & 3);     // pre-swizzled global 16B slot
  int scol = sslot * 16;

  int lr = rb * 64 + srow;
  int lrc = lr < cnt ? lr : cnt - 1;
  const u8* aptr = A + (size_t)s2r[base + lrc] * K + scol;
  const u8* bptr = WT + ((size_t)e * Hn + nb + srow) * K + scol;

  f32x4 zero = {0.f, 0.f, 0.f, 0.f};
  f32x4 acc[2][2];
#pragma unroll
  for (int m = 0; m < 2; m++)
#pragma unroll
    for (int n = 0; n < 2; n++) acc[m][n] = zero;

  int a_r = wr * 32 + (lane & 15);       // A fragment row
  int b_r = wc * 32 + (lane & 15);       // B fragment row
  int rkey = ((lane & 15) >> 1) & 3;     // (row>>1)&3 (row bases mult of 8 -> invariant)
  int slb = (lane >> 4) >> 1;            // logical slot sub-index (0/1)
  int half = ((lane >> 4) & 1) * 8;      // 8B half within slot

  for (int kt = 0; kt < NT; kt++) {
    gload16(aptr + kt * 64, &As[t * 16]);   // linear dest: row t>>2, slot t&3
    gload16(bptr + kt * 64, &Bs[t * 16]);
    __syncthreads();  // drains vmcnt before LDS reads
#pragma unroll
    for (int kk = 0; kk < 2; kk++) {
      long af[2], bfr[2];
#pragma unroll
      for (int m = 0; m < 2; m++)
        af[m] = *(const long*)(As + (a_r + m * 16) * 64 +
                               (((kk * 2 + slb) ^ rkey) << 4) + half);
#pragma unroll
      for (int n = 0; n < 2; n++)
        bfr[n] = *(const long*)(Bs + (b_r + n * 16) * 64 +
                                (((kk * 2 + slb) ^ rkey) << 4) + half);
#pragma unroll
      for (int m = 0; m < 2; m++)
#pragma unroll
        for (int n = 0; n < 2; n++)
          acc[m][n] = __builtin_amdgcn_mfma_f32_16x16x32_fp8_fp8(af[m], bfr[n], acc[m][n], 0, 0, 0);
    }
    __syncthreads();  // protect LDS before next stage
  }

  // epilogue: D layout col=lane&15, row=(lane>>4)*4+i; unscale 1/64 then bias+GELU
  const float INV = 1.0f / W1SCALE;
  int lr0 = rb * 64 + wr * 32;
#pragma unroll
  for (int m = 0; m < 2; m++) {
#pragma unroll
    for (int i = 0; i < 4; i++) {
      int orow = lr0 + m * 16 + (lane >> 4) * 4 + i;
      if (orow < cnt) {
        int slot = base + orow;
#pragma unroll
        for (int n = 0; n < 2; n++) {
          int col = nb + wc * 32 + n * 16 + (lane & 15);
          float v = acc[m][n][i] * INV + bias[e * Hn + col];
          float g = 0.5f * v * (1.0f + erff(v * 0.70710678118654752f));
          outH[(size_t)slot * Hn + col] = f2bf(g);
        }
      }
    }
  }
}

// ---- fc2 bf16 GEMM: 64x64xBK64 tile, 4 waves, r9/r14 structure, split-K=2 ----
template <int N, int K, int SPLITK>
__global__ __launch_bounds__(256, 8) void fc2_gemm_kernel(
    const ushort_t* __restrict__ A, const ushort_t* __restrict__ WT,
    const float* __restrict__ bias, const int* __restrict__ offsets,
    const int* __restrict__ counts,
    float* __restrict__ outL, float* __restrict__ outL2) {
  constexpr int NBL = N / 64;
  constexpr int KS = K / SPLITK;
  constexpr int NT = KS / 64;
  int e = blockIdx.z;
  int cnt = counts[e];
  int rb = blockIdx.y;
  if (rb * 64 >= cnt) return;
  int base = offsets[e];
  int ks = blockIdx.x / NBL;
  int nb = (blockIdx.x % NBL) * 64;
  int k0 = ks * KS;
  __shared__ __align__(16) ushort_t As[64 * 64];  // 8 KB
  __shared__ __align__(16) ushort_t Bs[64 * 64];  // 8 KB
  int t = threadIdx.x;
  int lane = t & 63, w = t >> 6;
  int wr = w >> 1, wc = w & 1;

  int srow = t >> 3;
  int scol = ((t & 7) ^ (srow & 7)) * 8;

  const ushort_t* aptr[2];
#pragma unroll
  for (int i = 0; i < 2; i++) {
    int lr = rb * 64 + i * 32 + srow;
    int lrc = lr < cnt ? lr : cnt - 1;
    aptr[i] = A + (size_t)(base + lrc) * K + k0 + scol;
  }
  const ushort_t* bptr = WT + ((size_t)e * N + nb + srow) * K + k0 + scol;

  f32x4 zero = {0.f, 0.f, 0.f, 0.f};
  f32x4 acc[2][2];
#pragma unroll
  for (int m = 0; m < 2; m++)
#pragma unroll
    for (int n = 0; n < 2; n++) acc[m][n] = zero;

  int a_r = wr * 32 + (lane & 15);
  int b_r = wc * 32 + (lane & 15);
  int axor = lane & 7;
  int c16 = lane >> 4;

  for (int kt = 0; kt < NT; kt++) {
#pragma unroll
    for (int i = 0; i < 2; i++) gload16(aptr[i] + kt * 64, &As[i * 2048 + t * 8]);
#pragma unroll
    for (int i = 0; i < 2; i++)
      gload16(bptr + (size_t)i * 32 * K + kt * 64, &Bs[i * 2048 + t * 8]);
    __syncthreads();
#pragma unroll
    for (int kk = 0; kk < 2; kk++) {
      bf16x8 af[2], bfr[2];
#pragma unroll
      for (int m = 0; m < 2; m++)
        af[m] = *(const bf16x8*)((const char*)As + (a_r + m * 16) * 128 +
                                 (((kk * 4 + c16) ^ axor) << 4));
#pragma unroll
      for (int n = 0; n < 2; n++)
        bfr[n] = *(const bf16x8*)((const char*)Bs + (b_r + n * 16) * 128 +
                                  (((kk * 4 + c16) ^ axor) << 4));
#pragma unroll
      for (int m = 0; m < 2; m++)
#pragma unroll
        for (int n = 0; n < 2; n++)
          acc[m][n] = __builtin_amdgcn_mfma_f32_16x16x32_bf16(af[m], bfr[n], acc[m][n], 0, 0, 0);
    }
    __syncthreads();
  }

  float* dst = (ks > 0) ? outL2 : outL;
  int lr0 = rb * 64 + wr * 32;
#pragma unroll
  for (int m = 0; m < 2; m++) {
#pragma unroll
    for (int i = 0; i < 4; i++) {
      int lr = lr0 + m * 16 + (lane >> 4) * 4 + i;
      if (lr < cnt) {
        int slot = base + lr;
#pragma unroll
        for (int n = 0; n < 2; n++) {
          int col = nb + wc * 32 + n * 16 + (lane & 15);
          float v = acc[m][n][i] + (ks == 0 ? bias[e * N + col] : 0.f);
          dst[(size_t)slot * N + col] = v;
        }
      }
    }
  }
}

// ---------------- combine: sum 2 split-K partials, logsoftmax over O=512, weighted sum ----------------
__device__ __forceinline__ float blk_reduce(float v, bool ismax) {
  __shared__ float sbuf[4];
  int lane = threadIdx.x & 63, w = threadIdx.x >> 6;
#pragma unroll
  for (int off = 32; off; off >>= 1) {
    float o = __shfl_down(v, off);
    v = ismax ? fmaxf(v, o) : (v + o);
  }
  __syncthreads();
  if (lane == 0) sbuf[w] = v;
  __syncthreads();
  float r = sbuf[0];
#pragma unroll
  for (int i = 1; i < 4; i++) r = ismax ? fmaxf(r, sbuf[i]) : (r + sbuf[i]);
  return r;
}

__global__ void combine_kernel(const float* __restrict__ l2a, const float* __restrict__ l2b,
                               const int* __restrict__ r2s, const float* __restrict__ gates,
                               float* __restrict__ out) {
  int b = blockIdx.x, t = threadIdx.x;
  float c0 = 0.f, c1 = 0.f;
#pragma unroll
  for (int k = 0; k < 2; k++) {
    int slot = r2s[2 * b + k];
    float g = gates[2 * b + k];
    const float* lp0 = l2a + (size_t)slot * On;
    const float* lp1 = l2b + (size_t)slot * On;
    float v0 = lp0[t] + lp1[t];
    float v1 = lp0[t + 256] + lp1[t + 256];
    float m = blk_reduce(fmaxf(v0, v1), true);
    float s = blk_reduce(expf(v0 - m) + expf(v1 - m), false);
    float lse = m + logf(s);
    c0 += g * expf(v0 - lse);
    c1 += g * expf(v1 - lse);
  }
  const float EPSv = 2.220446049250313e-16f;
  out[(size_t)b * On + t] = logf(fmaxf(c0, EPSv));
  out[(size_t)b * On + t + 256] = logf(fmaxf(c1, EPSv));
}

extern "C" void kernel_launch(void* const* d_in, const int* in_sizes, int n_in,
                              void* d_out, int out_size, void* d_ws, size_t ws_size,
                              hipStream_t stream) {
  const float* x = (const float*)d_in[0];
  const float* wgate = (const float*)d_in[1];
  const float* fc1w = (const float*)d_in[2];
  const float* fc1b = (const float*)d_in[3];
  const float* fc2w = (const float*)d_in[4];
  const float* fc2b = (const float*)d_in[5];
  float* out = (float*)d_out;

  char* ws = (char*)d_ws;
  size_t o = 0;
  u8* x_f8       = (u8*)(ws + o);       o += (size_t)Bn * Dn;             // 2 MB
  u8* w1t8       = (u8*)(ws + o);       o += (size_t)En * Hn * Dn;        // 16 MB [E][H][D] fp8
  ushort_t* w2t  = (ushort_t*)(ws + o); o += (size_t)En * On * Hn * 2;    // 16 MB [E][O][H]
  ushort_t* hbuf = (ushort_t*)(ws + o); o += (size_t)2 * Bn * Hn * 2;     // 16 MB [slot][H]
  float* l2buf   = (float*)(ws + o);    o += (size_t)2 * Bn * On * 4;     // 8 MB partial 0
  int* top_idx   = (int*)(ws + o);      o += (size_t)Bn * 2 * 4;
  float* gates   = (float*)(ws + o);    o += (size_t)Bn * 2 * 4;
  int* r2s       = (int*)(ws + o);      o += (size_t)Bn * 2 * 4;
  int* s2r       = (int*)(ws + o);      o += (size_t)2 * Bn * 4;
  int* counts    = (int*)(ws + o);      o += 64;
  int* offsets   = (int*)(ws + o);      o += 64;
  int* cursors   = (int*)(ws + o);      o += 64;
  // split-K partial 1 (8 MB) aliases w1t8 (16 MB): w1t8 is fully consumed by fc1
  // (completes before fc2 starts, same stream) and rewritten by prep each launch.
  float* l2buf1  = (float*)w1t8;

  hipLaunchKernelGGL(init_kernel, dim3(1), dim3(64), 0, stream, counts, cursors);
  hipLaunchKernelGGL(cast_x8_kernel, dim3(Bn * Dn / 16 / 256), dim3(256), 0, stream, x, x_f8);
  hipLaunchKernelGGL(prep_kernel, dim3(NB_G + NB_T1 + NB_T2), dim3(256), 0, stream,
                     x, wgate, fc1w, fc2w, w1t8, w2t, top_idx, gates, counts);
  hipLaunchKernelGGL(offsets_kernel, dim3(1), dim3(64), 0, stream, counts, offsets, cursors);
  hipLaunchKernelGGL(assign_kernel, dim3(Bn / 256), dim3(256), 0, stream,
                     top_idx, offsets, cursors, s2r, r2s);
  hipLaunchKernelGGL(fc1_fp8_kernel, dim3(Hn / 64, 32, En), dim3(256), 0, stream,
                     x_f8, w1t8, fc1b, offsets, counts, s2r, hbuf);
  hipLaunchKernelGGL((fc2_gemm_kernel<On, Hn, 2>), dim3((On / 64) * 2, 32, En), dim3(256),
                     0, stream, hbuf, w2t, fc2b, offsets, counts, l2buf, l2buf1);
  hipLaunchKernelGGL(combine_kernel, dim3(Bn), dim3(256), 0, stream, l2buf, l2buf1, r2s, gates, out);
}

// Round 17
// 115.238 us; speedup vs baseline: 1.1478x; 1.0837x over previous
//
#include <hip/hip_runtime.h>
#include <stdint.h>

#define Bn 2048
#define Dn 1024
#define Hn 2048
#define On 512
#define En 8

typedef float f32x4 __attribute__((ext_vector_type(4)));
typedef unsigned short ushort_t;
typedef unsigned char u8;

__device__ __forceinline__ ushort_t f2bf(float v) {
  union { float f; uint32_t u; } a; a.f = v;
  uint32_t u = a.u;
  return (ushort_t)((u + 0x7fffu + ((u >> 16) & 1u)) >> 16);  // RNE, finite inputs
}

__device__ __forceinline__ void gload16(const void* g, void* l) {
  __builtin_amdgcn_global_load_lds((const uint32_t*)g, (uint32_t*)l, 16, 0, 0);
}

// pack 4 floats -> 4 fp8 e4m3 in one dword
__device__ __forceinline__ int pk4_fp8(float a, float b, float c, float d) {
  int w = __builtin_amdgcn_cvt_pk_fp8_f32(a, b, 0, false);
  w = __builtin_amdgcn_cvt_pk_fp8_f32(c, d, w, true);
  return w;
}

__device__ __forceinline__ u8 f2fp8(float v) {
  int w = __builtin_amdgcn_cvt_pk_fp8_f32(v, v, 0, false);
  return (u8)(w & 0xff);
}

// ---------------- init: zero counts/cursors every launch (determinism) ----------------
__global__ void init_kernel(int* counts, int* cursors) {
  int t = threadIdx.x;
  if (t < En) { counts[t] = 0; cursors[t] = 0; }
}

// ---------------- cast x f32 -> fp8 (16 contiguous elems per thread) ----------------
__global__ __launch_bounds__(256) void cast_x8_kernel(const float* __restrict__ in,
                                                      u8* __restrict__ out) {
  int i = blockIdx.x * 256 + threadIdx.x;
  const float4* p = (const float4*)in + (size_t)i * 4;
  float4 a = p[0], b = p[1], c = p[2], d = p[3];
  int4 o;
  o.x = pk4_fp8(a.x, a.y, a.z, a.w);
  o.y = pk4_fp8(b.x, b.y, b.z, b.w);
  o.z = pk4_fp8(c.x, c.y, c.z, c.w);
  o.w = pk4_fp8(d.x, d.y, d.z, d.w);
  *(int4*)(out + (size_t)i * 16) = o;
}

// ====== fused prep: gating | tcast fc1_w -> fp8 (x64) | tcast fc2_w -> fp8 (x64) ======
#define NB_G (Bn / 8)
#define NB_T1 ((Dn / 64) * (Hn / 64) * En)
#define NB_T2 ((Hn / 64) * (On / 64) * En)
#define WSCALE 64.0f

// 64x64 transpose tile -> fp8 out (scaled by WSCALE), writes 16B per thread
__device__ __forceinline__ void tcast64_f8(const float* __restrict__ inp,
                                           u8* __restrict__ outp,
                                           int R, int C, int r0, int c0, float* tile) {
  int t = threadIdx.x;
  int rr = t >> 4, cc4 = (t & 15) * 4;
#pragma unroll
  for (int j = 0; j < 4; j++) {
    float4 v = *(const float4*)&inp[(size_t)(r0 + j * 16 + rr) * C + c0 + cc4];
    float* tp = &tile[(j * 16 + rr) * 65 + cc4];
    tp[0] = v.x; tp[1] = v.y; tp[2] = v.z; tp[3] = v.w;
  }
  __syncthreads();
  int orow = t >> 2, g = t & 3;
  int4 o;
#pragma unroll
  for (int q = 0; q < 4; q++) {
    float v0 = tile[(g * 16 + q * 4 + 0) * 65 + orow] * WSCALE;
    float v1 = tile[(g * 16 + q * 4 + 1) * 65 + orow] * WSCALE;
    float v2 = tile[(g * 16 + q * 4 + 2) * 65 + orow] * WSCALE;
    float v3 = tile[(g * 16 + q * 4 + 3) * 65 + orow] * WSCALE;
    ((int*)&o)[q] = pk4_fp8(v0, v1, v2, v3);
  }
  *(int4*)&outp[(size_t)(c0 + orow) * R + r0 + g * 16] = o;
}

__global__ __launch_bounds__(256) void prep_kernel(
    const float* __restrict__ x, const float* __restrict__ wg,
    const float* __restrict__ fc1w, const float* __restrict__ fc2w,
    u8* __restrict__ w1t8, u8* __restrict__ w2t8,
    int* __restrict__ top_idx, float* __restrict__ gates, int* __restrict__ counts) {
  __shared__ float smem[En * Dn];  // 32 KB
  __shared__ int lcnt[En];
  int bid = blockIdx.x;
  int t = threadIdx.x;

  if (bid < NB_G) {
    float* wgs = smem;
    for (int i = t; i < Dn * En; i += 256) {
      int d = i >> 3, e = i & 7;
      wgs[e * Dn + d] = wg[i];  // wg is [d][e]
    }
    if (t < En) lcnt[t] = 0;
    __syncthreads();
    int w = t >> 6, lane = t & 63;
#pragma unroll
    for (int r = 0; r < 2; r++) {
      int b = bid * 8 + w * 2 + r;
      const float* xr = x + (size_t)b * Dn;
      float xv[16];
#pragma unroll
      for (int j = 0; j < 16; j++) xv[j] = xr[lane + j * 64];
      float acc[En];
#pragma unroll
      for (int e = 0; e < En; e++) acc[e] = 0.f;
#pragma unroll
      for (int j = 0; j < 16; j++) {
        int d = lane + j * 64;
#pragma unroll
        for (int e = 0; e < En; e++) acc[e] += xv[j] * wgs[e * Dn + d];
      }
#pragma unroll
      for (int off = 32; off; off >>= 1) {
#pragma unroll
        for (int e = 0; e < En; e++) acc[e] += __shfl_down(acc[e], off);
      }
      if (lane == 0) {
        float best = -1e30f, second = -1e30f; int bi = 0, si = 0;
#pragma unroll
        for (int e = 0; e < En; e++) {
          float l = acc[e];
          if (l > best) { second = best; si = bi; best = l; bi = e; }
          else if (l > second) { second = l; si = e; }
        }
        float e1 = expf(second - best);
        float inv = 1.f / (1.f + e1);
        top_idx[2 * b] = bi; top_idx[2 * b + 1] = si;
        gates[2 * b] = inv;  gates[2 * b + 1] = e1 * inv;
        atomicAdd(&lcnt[bi], 1);
        atomicAdd(&lcnt[si], 1);
      }
    }
    __syncthreads();
    if (t < En) {
      int c = lcnt[t];
      if (c) atomicAdd(&counts[t], c);
    }
  } else if (bid < NB_G + NB_T1) {
    int idx = bid - NB_G;
    constexpr int TPE = (Dn / 64) * (Hn / 64);
    int z = idx / TPE, rem = idx % TPE;
    int r0 = (rem / (Hn / 64)) * 64, c0 = (rem % (Hn / 64)) * 64;
    tcast64_f8(fc1w + (size_t)z * Dn * Hn, w1t8 + (size_t)z * Dn * Hn, Dn, Hn, r0, c0, smem);
  } else {
    int idx = bid - NB_G - NB_T1;
    constexpr int TPE = (Hn / 64) * (On / 64);
    int z = idx / TPE, rem = idx % TPE;
    int r0 = (rem / (On / 64)) * 64, c0 = (rem % (On / 64)) * 64;
    tcast64_f8(fc2w + (size_t)z * Hn * On, w2t8 + (size_t)z * Hn * On, Hn, On, r0, c0, smem);
  }
}

// ---------------- offsets (exclusive prefix over 8 counts) ----------------
__global__ void offsets_kernel(const int* counts, int* offsets, int* cursors) {
  if (threadIdx.x == 0) {
    int s = 0;
    for (int e = 0; e < En; e++) { offsets[e] = s; s += counts[e]; }
  }
  if (threadIdx.x < En) cursors[threadIdx.x] = 0;
}

// ---------------- assign rows to compact slots ----------------
__global__ void assign_kernel(const int* __restrict__ top_idx, const int* __restrict__ offsets,
                              int* cursors, int* __restrict__ s2r, int* __restrict__ r2s) {
  int b = blockIdx.x * 256 + threadIdx.x;
  if (b >= Bn) return;
#pragma unroll
  for (int k = 0; k < 2; k++) {
    int e = top_idx[2 * b + k];
    int pos = atomicAdd(&cursors[e], 1);
    int slot = offsets[e] + pos;
    s2r[slot] = b;
    r2s[2 * b + k] = slot;
  }
}

// ---- fp8 grouped GEMM: 64x64 x 64B-K-step, 4 waves (2Mx2N), mfma_f32_16x16x32_fp8_fp8 ----
// r16-proven structure. W pre-scaled x64 -> epilogue unscales 1/64 before bias.
// Swizzle: 16B slot s of row r holds global slot (s ^ ((r>>1)&3)); linear-dest gload_lds
// + pre-swizzled source (rule #21); uniform 2-way LDS reads (free, m136).
// FC1: A gathered via s2r, epilogue bias+GELU -> fp8 out. Else: f32 split-K partials.
template <bool FC1, int N, int K, int SPLITK>
__global__ __launch_bounds__(256, 8) void fp8_gemm_kernel(
    const u8* __restrict__ A, const u8* __restrict__ WT,
    const float* __restrict__ bias, const int* __restrict__ offsets,
    const int* __restrict__ counts, const int* __restrict__ s2r,
    u8* __restrict__ outH8, float* __restrict__ outL, float* __restrict__ outL2) {
  constexpr int NBL = N / 64;
  constexpr int KS = K / SPLITK;
  constexpr int NT = KS / 64;
  int e = blockIdx.z;
  int cnt = counts[e];
  int rb = blockIdx.y;
  if (rb * 64 >= cnt) return;
  int base = offsets[e];
  int ks = blockIdx.x / NBL;
  int nb = (blockIdx.x % NBL) * 64;
  int k0 = ks * KS;
  __shared__ __align__(16) u8 As[64 * 64];  // 4 KB
  __shared__ __align__(16) u8 Bs[64 * 64];  // 4 KB
  int t = threadIdx.x;
  int lane = t & 63, w = t >> 6;
  int wr = w >> 1, wc = w & 1;

  int srow = t >> 2;                           // 0..63 staging row
  int sslot = (t & 3) ^ ((srow >> 1) & 3);     // pre-swizzled global 16B slot
  int scol = sslot * 16;

  int lr = rb * 64 + srow;
  int lrc = lr < cnt ? lr : cnt - 1;
  const u8* aptr = A + (size_t)(FC1 ? s2r[base + lrc] : (base + lrc)) * K + k0 + scol;
  const u8* bptr = WT + ((size_t)e * N + nb + srow) * K + k0 + scol;

  f32x4 zero = {0.f, 0.f, 0.f, 0.f};
  f32x4 acc[2][2];
#pragma unroll
  for (int m = 0; m < 2; m++)
#pragma unroll
    for (int n = 0; n < 2; n++) acc[m][n] = zero;

  int a_r = wr * 32 + (lane & 15);       // A fragment row
  int b_r = wc * 32 + (lane & 15);       // B fragment row
  int rkey = ((lane & 15) >> 1) & 3;     // (row>>1)&3 (row bases mult of 16 -> invariant)
  int slb = (lane >> 4) >> 1;            // logical 16B-slot sub-index (0/1)
  int half = ((lane >> 4) & 1) * 8;      // 8B half within slot

  for (int kt = 0; kt < NT; kt++) {
    gload16(aptr + kt * 64, &As[t * 16]);   // linear dest: row t>>2, slot t&3
    gload16(bptr + kt * 64, &Bs[t * 16]);
    __syncthreads();  // drains vmcnt before LDS reads
#pragma unroll
    for (int kk = 0; kk < 2; kk++) {
      long af[2], bfr[2];
#pragma unroll
      for (int m = 0; m < 2; m++)
        af[m] = *(const long*)(As + (a_r + m * 16) * 64 +
                               (((kk * 2 + slb) ^ rkey) << 4) + half);
#pragma unroll
      for (int n = 0; n < 2; n++)
        bfr[n] = *(const long*)(Bs + (b_r + n * 16) * 64 +
                                (((kk * 2 + slb) ^ rkey) << 4) + half);
#pragma unroll
      for (int m = 0; m < 2; m++)
#pragma unroll
        for (int n = 0; n < 2; n++)
          acc[m][n] = __builtin_amdgcn_mfma_f32_16x16x32_fp8_fp8(af[m], bfr[n], acc[m][n], 0, 0, 0);
    }
    __syncthreads();  // protect LDS before next stage
  }

  // epilogue: D layout col=lane&15, row=(lane>>4)*4+i; unscale 1/64
  const float INV = 1.0f / WSCALE;
  float* dst = (SPLITK > 1 && ks > 0) ? outL2 : outL;
  int lr0 = rb * 64 + wr * 32;
#pragma unroll
  for (int m = 0; m < 2; m++) {
#pragma unroll
    for (int i = 0; i < 4; i++) {
      int orow = lr0 + m * 16 + (lane >> 4) * 4 + i;
      if (orow < cnt) {
        int slot = base + orow;
#pragma unroll
        for (int n = 0; n < 2; n++) {
          int col = nb + wc * 32 + n * 16 + (lane & 15);
          if (FC1) {
            float v = acc[m][n][i] * INV + bias[e * N + col];
            float g = 0.5f * v * (1.0f + erff(v * 0.70710678118654752f));
            outH8[(size_t)slot * N + col] = f2fp8(g);
          } else {
            float v = acc[m][n][i] * INV + (ks == 0 ? bias[e * N + col] : 0.f);
            dst[(size_t)slot * N + col] = v;
          }
        }
      }
    }
  }
}

// ---------------- combine: sum 2 split-K partials, logsoftmax over O=512, weighted sum ----------------
__device__ __forceinline__ float blk_reduce(float v, bool ismax) {
  __shared__ float sbuf[4];
  int lane = threadIdx.x & 63, w = threadIdx.x >> 6;
#pragma unroll
  for (int off = 32; off; off >>= 1) {
    float o = __shfl_down(v, off);
    v = ismax ? fmaxf(v, o) : (v + o);
  }
  __syncthreads();
  if (lane == 0) sbuf[w] = v;
  __syncthreads();
  float r = sbuf[0];
#pragma unroll
  for (int i = 1; i < 4; i++) r = ismax ? fmaxf(r, sbuf[i]) : (r + sbuf[i]);
  return r;
}

__global__ void combine_kernel(const float* __restrict__ l2a, const float* __restrict__ l2b,
                               const int* __restrict__ r2s, const float* __restrict__ gates,
                               float* __restrict__ out) {
  int b = blockIdx.x, t = threadIdx.x;
  float c0 = 0.f, c1 = 0.f;
#pragma unroll
  for (int k = 0; k < 2; k++) {
    int slot = r2s[2 * b + k];
    float g = gates[2 * b + k];
    const float* lp0 = l2a + (size_t)slot * On;
    const float* lp1 = l2b + (size_t)slot * On;
    float v0 = lp0[t] + lp1[t];
    float v1 = lp0[t + 256] + lp1[t + 256];
    float m = blk_reduce(fmaxf(v0, v1), true);
    float s = blk_reduce(expf(v0 - m) + expf(v1 - m), false);
    float lse = m + logf(s);
    c0 += g * expf(v0 - lse);
    c1 += g * expf(v1 - lse);
  }
  const float EPSv = 2.220446049250313e-16f;
  out[(size_t)b * On + t] = logf(fmaxf(c0, EPSv));
  out[(size_t)b * On + t + 256] = logf(fmaxf(c1, EPSv));
}

extern "C" void kernel_launch(void* const* d_in, const int* in_sizes, int n_in,
                              void* d_out, int out_size, void* d_ws, size_t ws_size,
                              hipStream_t stream) {
  const float* x = (const float*)d_in[0];
  const float* wgate = (const float*)d_in[1];
  const float* fc1w = (const float*)d_in[2];
  const float* fc1b = (const float*)d_in[3];
  const float* fc2w = (const float*)d_in[4];
  const float* fc2b = (const float*)d_in[5];
  float* out = (float*)d_out;

  char* ws = (char*)d_ws;
  size_t o = 0;
  u8* x_f8     = (u8*)(ws + o);    o += (size_t)Bn * Dn;          // 2 MB
  u8* w1t8     = (u8*)(ws + o);    o += (size_t)En * Hn * Dn;     // 16 MB [E][H][D] fp8
  u8* w2t8     = (u8*)(ws + o);    o += (size_t)En * On * Hn;     // 8 MB  [E][O][H] fp8
  u8* hbuf8    = (u8*)(ws + o);    o += (size_t)2 * Bn * Hn;      // 4 MB  [slot][H] fp8
  float* l2buf = (float*)(ws + o); o += (size_t)2 * Bn * On * 4;  // 8 MB partial 0
  int* top_idx = (int*)(ws + o);   o += (size_t)Bn * 2 * 4;
  float* gates = (float*)(ws + o); o += (size_t)Bn * 2 * 4;
  int* r2s     = (int*)(ws + o);   o += (size_t)Bn * 2 * 4;
  int* s2r     = (int*)(ws + o);   o += (size_t)2 * Bn * 4;
  int* counts  = (int*)(ws + o);   o += 64;
  int* offsets = (int*)(ws + o);   o += 64;
  int* cursors = (int*)(ws + o);   o += 64;
  // split-K partial 1 (8 MB) aliases w1t8 (16 MB): w1t8 is fully consumed by fc1
  // (completes before fc2 starts, same stream) and rewritten by prep each launch.
  float* l2buf1 = (float*)w1t8;

  hipLaunchKernelGGL(init_kernel, dim3(1), dim3(64), 0, stream, counts, cursors);
  hipLaunchKernelGGL(cast_x8_kernel, dim3(Bn * Dn / 16 / 256), dim3(256), 0, stream, x, x_f8);
  hipLaunchKernelGGL(prep_kernel, dim3(NB_G + NB_T1 + NB_T2), dim3(256), 0, stream,
                     x, wgate, fc1w, fc2w, w1t8, w2t8, top_idx, gates, counts);
  hipLaunchKernelGGL(offsets_kernel, dim3(1), dim3(64), 0, stream, counts, offsets, cursors);
  hipLaunchKernelGGL(assign_kernel, dim3(Bn / 256), dim3(256), 0, stream,
                     top_idx, offsets, cursors, s2r, r2s);
  hipLaunchKernelGGL((fp8_gemm_kernel<true, Hn, Dn, 1>), dim3(Hn / 64, 32, En), dim3(256),
                     0, stream, x_f8, w1t8, fc1b, offsets, counts, s2r, hbuf8,
                     (float*)nullptr, (float*)nullptr);
  hipLaunchKernelGGL((fp8_gemm_kernel<false, On, Hn, 2>), dim3((On / 64) * 2, 32, En), dim3(256),
                     0, stream, hbuf8, w2t8, fc2b, offsets, counts, s2r, (u8*)nullptr,
                     l2buf, l2buf1);
  hipLaunchKernelGGL(combine_kernel, dim3(Bn), dim3(256), 0, stream, l2buf, l2buf1, r2s, gates, out);
}